// Round 5
// baseline (1304.756 us; speedup 1.0000x reference)
//
#include <hip/hip_runtime.h>

#define GAS __attribute__((address_space(1)))
#define LAS __attribute__((address_space(3)))

typedef __attribute__((ext_vector_type(8))) short bf16x8;
typedef __attribute__((ext_vector_type(4))) float f32x4;
typedef __attribute__((ext_vector_type(2))) float f32x2;

static constexpr int Bb = 16, Ll = 2048, Hh = 512, Vv = 32000, H2 = 1024;
static constexpr int Mtot = Bb * Ll;  // 32768
static constexpr float LRc = 0.01f, EPSc = 1e-5f;

// ---- ws layout (bytes) ----
static constexpr size_t OFF_X    = 0;                                   // Mtot*Hh*4
static constexpr size_t OFF_EBF  = OFF_X   + (size_t)Mtot * Hh * 4;     // Vv*Hh*2
static constexpr size_t OFF_W1BF = OFF_EBF + (size_t)Vv * Hh * 2;       // H2*Hh*2
static constexpr size_t OFF_W2BF = OFF_W1BF + (size_t)H2 * Hh * 2;      // Hh*H2*2
static constexpr size_t OFF_CTX  = OFF_W2BF + (size_t)Hh * H2 * 2;      // Bb*Hh*4
static constexpr size_t OFF_FF1  = OFF_CTX + (size_t)Bb * Hh * 4;       // chunk of ff1 (bf16)

__device__ inline unsigned short f2bf(float f) {  // RNE f32 -> bf16
  unsigned u = __float_as_uint(f);
  return (unsigned short)((u + 0x7fffu + ((u >> 16) & 1u)) >> 16);
}

__device__ inline f32x2 pk_fma(f32x2 a, f32x2 b, f32x2 c) { return a * b + c; }

// Batched full-wave reduce: N independent chains, 6 DPP stages each, chains
// textually interleaved per stage so in-order issue hides DPP latency.
// Totals valid in lane 63 ONLY.
template <int N>
__device__ inline void wreduceN(float* ch) {
#define WST(CTRL)                                                              \
  {                                                                            \
    _Pragma("unroll") for (int c = 0; c < N; ++c) {                            \
      int t_ = __builtin_amdgcn_update_dpp(0, __float_as_int(ch[c]), CTRL,     \
                                           0xf, 0xf, true);                    \
      ch[c] += __int_as_float(t_);                                             \
    }                                                                          \
  }
  WST(0x111)  // row_shr:1
  WST(0x112)  // row_shr:2
  WST(0x114)  // row_shr:4
  WST(0x118)  // row_shr:8
  WST(0x142)  // row_bcast:15
  WST(0x143)  // row_bcast:31 -> lane63 = total
#undef WST
}

// ---------------- f32 -> bf16 conversion ----------------
__global__ __launch_bounds__(256) void cvt_bf16_kernel(const float* __restrict__ src,
                                                       unsigned short* __restrict__ dst, int n8) {
  int stride = gridDim.x * blockDim.x;
  for (int i = blockIdx.x * blockDim.x + threadIdx.x; i < n8; i += stride) {
    const float4* p = (const float4*)(src + (size_t)i * 8);
    float4 a = p[0], b = p[1];
    uint4 o;
    o.x = f2bf(a.x) | ((unsigned)f2bf(a.y) << 16);
    o.y = f2bf(a.z) | ((unsigned)f2bf(a.w) << 16);
    o.z = f2bf(b.x) | ((unsigned)f2bf(b.y) << 16);
    o.w = f2bf(b.z) | ((unsigned)f2bf(b.w) << 16);
    *(uint4*)(dst + (size_t)i * 8) = o;
  }
}

// ---------------- bf16 GEMM, B^T layout, 128x128 tile, BK=32 (m97 structure) ----------------
template <int KTOT, bool GATHER, bool RELUOUT>
__global__ __launch_bounds__(256) void gemm_bt(const unsigned short* __restrict__ Abase,
                                               const int* __restrict__ seq, int seq_off,
                                               const unsigned short* __restrict__ Bmat,
                                               const float* __restrict__ bias,
                                               unsigned short* __restrict__ outb,
                                               float* __restrict__ outf,
                                               int out_row_off, int ldout) {
  __shared__ unsigned short As[128 * 32];
  __shared__ unsigned short Bs[128 * 32];
  __shared__ unsigned long long aoff[128];
  const int tid = threadIdx.x;
  const int m0 = blockIdx.x * 128, n0 = blockIdx.y * 128;

  if (tid < 128) {
    long long r;
    if (GATHER) r = (long long)seq[seq_off + m0 + tid] * KTOT;
    else        r = (long long)(m0 + tid) * KTOT;
    aoff[tid] = (unsigned long long)r;
  }
  __syncthreads();

  const int srow = tid >> 2;
  const int scol = (tid & 3) * 8;
  const int wave = tid >> 6;
  const int lane = tid & 63;
  const int wr = wave >> 1, wc = wave & 1;
  const int fr = lane & 15;
  const int fk = (lane >> 4) * 8;

  f32x4 acc[4][4] = {};

  for (int k0 = 0; k0 < KTOT; k0 += 32) {
#pragma unroll
    for (int i = 0; i < 2; ++i) {
      const unsigned short* ga = Abase + aoff[i * 64 + srow] + k0 + scol;
      __builtin_amdgcn_global_load_lds((const GAS void*)ga,
          (LAS void*)((char*)As + i * 4096 + wave * 1024), 16, 0, 0);
      const unsigned short* gb = Bmat + (size_t)(n0 + i * 64 + srow) * KTOT + k0 + scol;
      __builtin_amdgcn_global_load_lds((const GAS void*)gb,
          (LAS void*)((char*)Bs + i * 4096 + wave * 1024), 16, 0, 0);
    }
    __syncthreads();
    bf16x8 af[4], bfr[4];
#pragma unroll
    for (int m = 0; m < 4; ++m)
      af[m] = *(const bf16x8*)&As[(wr * 64 + m * 16 + fr) * 32 + fk];
#pragma unroll
    for (int n = 0; n < 4; ++n)
      bfr[n] = *(const bf16x8*)&Bs[(wc * 64 + n * 16 + fr) * 32 + fk];
#pragma unroll
    for (int m = 0; m < 4; ++m)
#pragma unroll
      for (int n = 0; n < 4; ++n)
        acc[m][n] = __builtin_amdgcn_mfma_f32_16x16x32_bf16(af[m], bfr[n], acc[m][n], 0, 0, 0);
    __syncthreads();
  }

  float bv[4];
#pragma unroll
  for (int n = 0; n < 4; ++n) bv[n] = bias[n0 + wc * 64 + n * 16 + fr];
#pragma unroll
  for (int m = 0; m < 4; ++m) {
#pragma unroll
    for (int n = 0; n < 4; ++n) {
#pragma unroll
      for (int j = 0; j < 4; ++j) {
        int rl = wr * 64 + m * 16 + ((lane >> 4) << 2) + j;
        int col = n0 + wc * 64 + n * 16 + fr;
        float v = acc[m][n][j] + bv[n];
        size_t off = (size_t)(out_row_off + m0 + rl) * ldout + col;
        if (RELUOUT) { v = fmaxf(v, 0.f); outb[off] = f2bf(v); }
        else outf[off] = v;
      }
    }
  }
}

// ---------------- residual add + LayerNorm ----------------
__global__ __launch_bounds__(256) void ln_kernel(float* __restrict__ xbuf,
                                                 const float* __restrict__ embed,
                                                 const int* __restrict__ seq,
                                                 const float* __restrict__ lnw,
                                                 const float* __restrict__ lnb) {
  int row = blockIdx.x * 4 + (threadIdx.x >> 6);
  int lane = threadIdx.x & 63;
  int c = lane * 8;
  int s = seq[row];
  float* xr = xbuf + (size_t)row * Hh;
  const float* hr = embed + (size_t)s * Hh;
  float4 f0 = *(const float4*)(xr + c), f1 = *(const float4*)(xr + c + 4);
  float4 h0 = *(const float4*)(hr + c), h1 = *(const float4*)(hr + c + 4);
  float x[8] = {f0.x + h0.x, f0.y + h0.y, f0.z + h0.z, f0.w + h0.w,
                f1.x + h1.x, f1.y + h1.y, f1.z + h1.z, f1.w + h1.w};
  float sm = 0.f, sq = 0.f;
#pragma unroll
  for (int u = 0; u < 8; ++u) { sm += x[u]; sq += x[u] * x[u]; }
#pragma unroll
  for (int m = 1; m < 64; m <<= 1) { sm += __shfl_xor(sm, m, 64); sq += __shfl_xor(sq, m, 64); }
  float mu = sm * (1.f / 512.f);
  float var = sq * (1.f / 512.f) - mu * mu;
  float rs = rsqrtf(var + EPSc);
  float y[8];
#pragma unroll
  for (int u = 0; u < 8; ++u) y[u] = (x[u] - mu) * rs * lnw[c + u] + lnb[c + u];
  *(float4*)(xr + c) = make_float4(y[0], y[1], y[2], y[3]);
  *(float4*)(xr + c + 4) = make_float4(y[4], y[5], y[6], y[7]);
}

// ---------------- TTT scan v5: 2 cooperating waves per batch ----------------
// Row-split: wave w owns W1 rows 4w..4w+3 and W2 rows {8*lane+4w..8*lane+4w+3}.
// Shadow identity (validated R2/R3): z_{t+1} = S(t) - LR*dz_t*(kappa_t+1),
//   S(t) = W1_t k_{t+1} + b1_t, kappa_t = k_t . k_{t+1}.
// Per step each wave: own pred/d/dhp half, own 4 S-chains, 8 dh-partial
// chains, kappa -> ONE batched 13-chain DPP reduce; lane63 writes 13 floats
// to LDS; one __syncthreads(); next step combines.
__global__ __launch_bounds__(128, 1) void ttt_kernel(const float* __restrict__ hidden,
                                                     const float* __restrict__ w1_0,
                                                     const float* __restrict__ b1_0,
                                                     const float* __restrict__ w2_0,
                                                     const float* __restrict__ b2_0,
                                                     float* __restrict__ ctx) {
  const int b = blockIdx.x;
  const int tid = threadIdx.x;
  const int w = tid >> 6;      // wave id 0/1
  const int lane = tid & 63;
  const int c0 = lane * 8;
  const float* hb = hidden + (size_t)b * Ll * Hh;
  const float scale = 2.0f / 512.0f;

  __shared__ float4 exS[2][2];     // [buf][wave] S totals (+b1) for its 4 j's
  __shared__ float4 exD[2][2][2];  // [buf][wave][2] raw dh partial totals (8 j's)
  __shared__ float  exK[2];        // [buf] kappa (written by wave 1)
  __shared__ float4 exQ[2];        // query z halves

  // ---- weights (own halves) ----
  f32x2 W1h[4][4];  // rows j=4w+jj, cols c0+2p..c0+2p+1
  float B1h[4];
  f32x2 W2h[4][4];  // rows i=8*lane+4w+uu, cols 2p..2p+1 (full 8 cols)
  float B2h[4];
#pragma unroll
  for (int jj = 0; jj < 4; ++jj) {
    const float* r = w1_0 + (size_t)(4 * w + jj) * Hh + c0;
    float4 a = *(const float4*)r, d = *(const float4*)(r + 4);
    W1h[jj][0] = f32x2{a.x, a.y}; W1h[jj][1] = f32x2{a.z, a.w};
    W1h[jj][2] = f32x2{d.x, d.y}; W1h[jj][3] = f32x2{d.z, d.w};
    B1h[jj] = b1_0[4 * w + jj];
  }
#pragma unroll
  for (int uu = 0; uu < 4; ++uu) {
    const float* r = w2_0 + (size_t)(8 * lane + 4 * w + uu) * 8;
    float4 a = *(const float4*)r, d = *(const float4*)(r + 4);
    W2h[uu][0] = f32x2{a.x, a.y}; W2h[uu][1] = f32x2{a.z, a.w};
    W2h[uu][2] = f32x2{d.x, d.y}; W2h[uu][3] = f32x2{d.z, d.w};
  }
  {
    float4 e = *(const float4*)(b2_0 + 8 * lane + 4 * w);
    B2h[0] = e.x; B2h[1] = e.y; B2h[2] = e.z; B2h[3] = e.w;
  }

  // ---- k/v streams ----
  f32x2 Kp[4], Kc[4], Kn[4];
  float Vq[4];
  {
    const float* p0 = hb + c0;  // k_0 = row 0
    float4 a = *(const float4*)p0, d = *(const float4*)(p0 + 4);
    Kc[0] = f32x2{a.x, a.y}; Kc[1] = f32x2{a.z, a.w};
    Kc[2] = f32x2{d.x, d.y}; Kc[3] = f32x2{d.z, d.w};
    const float* p1 = hb + 2 * Hh + c0;  // k_1 = row 2
    float4 e = *(const float4*)p1, f = *(const float4*)(p1 + 4);
    Kn[0] = f32x2{e.x, e.y}; Kn[1] = f32x2{e.z, e.w};
    Kn[2] = f32x2{f.x, f.y}; Kn[3] = f32x2{f.z, f.w};
#pragma unroll
    for (int p = 0; p < 4; ++p) Kp[p] = Kc[p];  // dummy (dz_{-1}=0)
    float4 g = *(const float4*)(hb + Hh + 8 * lane + 4 * w);  // v_0 = row 1
    Vq[0] = g.x; Vq[1] = g.y; Vq[2] = g.z; Vq[3] = g.w;
  }

  // ---- prologue: S_pre = W1_0 k_0 + b1 -> buf 1; dh=0; kappa=-1 ----
  {
    float ch[4];
#pragma unroll
    for (int jj = 0; jj < 4; ++jj) {
      f32x2 a = pk_fma(W1h[jj][0], Kc[0], pk_fma(W1h[jj][1], Kc[1], f32x2{0.f, 0.f}));
      f32x2 c = pk_fma(W1h[jj][2], Kc[2], pk_fma(W1h[jj][3], Kc[3], f32x2{0.f, 0.f}));
      f32x2 s = a + c;
      ch[jj] = s.x + s.y;
    }
    wreduceN<4>(ch);
    if (lane == 63) {
      exS[1][w] = make_float4(ch[0] + B1h[0], ch[1] + B1h[1], ch[2] + B1h[2], ch[3] + B1h[3]);
      exD[1][w][0] = make_float4(0.f, 0.f, 0.f, 0.f);
      exD[1][w][1] = make_float4(0.f, 0.f, 0.f, 0.f);
      if (w == 1) exK[1] = -1.0f;  // (kappa+1)=0 -> zu(0)=S_pre
    }
  }
  float zu[8] = {0.f, 0.f, 0.f, 0.f, 0.f, 0.f, 0.f, 0.f};
  __syncthreads();

#pragma unroll 1
  for (int t = 0; t < 1023; ++t) {
    const int pb = (t + 1) & 1, cb = t & 1;
    // ---- uniform LDS reads (prev step's totals) ----
    float4 s0 = exS[pb][0], s1 = exS[pb][1];
    float4 da0 = exD[pb][0][0], da1 = exD[pb][0][1];
    float4 db0 = exD[pb][1][0], db1 = exD[pb][1][1];
    float kap = exK[pb];

    // ---- prefetch k_{t+2}, v_{t+1} (consumed at rotate) ----
    const float* kr = hb + (size_t)(2 * t + 4) * Hh + c0;
    float4 ka = *(const float4*)kr, kb4 = *(const float4*)(kr + 4);
    float4 vn = *(const float4*)(hb + (size_t)(2 * t + 3) * Hh + 8 * lane + 4 * w);

    // ---- finalize step t-1: dz, zu(t), W1_t, b1_t ----
    float dh[8] = {da0.x + db0.x, da0.y + db0.y, da0.z + db0.z, da0.w + db0.w,
                   da1.x + db1.x, da1.y + db1.y, da1.z + db1.z, da1.w + db1.w};
    float dz[8];
#pragma unroll
    for (int j = 0; j < 8; ++j) dz[j] = (zu[j] > 0.f) ? dh[j] : 0.f;
    float Sv[8] = {s0.x, s0.y, s0.z, s0.w, s1.x, s1.y, s1.z, s1.w};
    float t1 = -LRc * (kap + 1.f);
#pragma unroll
    for (int j = 0; j < 8; ++j) zu[j] = fmaf(t1, dz[j], Sv[j]);
#pragma unroll
    for (int jj = 0; jj < 4; ++jj) {
      float g = -LRc * dz[4 * w + jj];
      f32x2 gv = {g, g};
#pragma unroll
      for (int p = 0; p < 4; ++p) W1h[jj][p] = pk_fma(gv, Kp[p], W1h[jj][p]);
      B1h[jj] = fmaf(-LRc, dz[4 * w + jj], B1h[jj]);
    }

    // ---- step t forward: h, pred/d (own rows) ----
    float hu[8];
#pragma unroll
    for (int j = 0; j < 8; ++j) hu[j] = fmaxf(zu[j], 0.f);
    f32x2 h2[4];
#pragma unroll
    for (int p = 0; p < 4; ++p) h2[p] = f32x2{hu[2 * p], hu[2 * p + 1]};

    float dloc[4];
    f32x2 dd[4];
#pragma unroll
    for (int uu = 0; uu < 4; ++uu) {
      f32x2 a = pk_fma(W2h[uu][0], h2[0], pk_fma(W2h[uu][1], h2[1], f32x2{0.f, 0.f}));
      f32x2 c = pk_fma(W2h[uu][2], h2[2], pk_fma(W2h[uu][3], h2[3], f32x2{0.f, 0.f}));
      f32x2 s = a + c;
      float pred = s.x + s.y + B2h[uu];
      float dv = (pred - Vq[uu]) * scale;
      dloc[uu] = dv;
      dd[uu] = f32x2{dv, dv};
    }

    // ---- batched chains: dh partials (8) + own S(t) (4) + kappa (1) ----
    float ch[13];
    {
      f32x2 dq[4] = {f32x2{0.f, 0.f}, f32x2{0.f, 0.f}, f32x2{0.f, 0.f}, f32x2{0.f, 0.f}};
#pragma unroll
      for (int uu = 0; uu < 4; ++uu)
#pragma unroll
        for (int p = 0; p < 4; ++p) dq[p] = pk_fma(W2h[uu][p], dd[uu], dq[p]);
#pragma unroll
      for (int p = 0; p < 4; ++p) { ch[2 * p] = dq[p].x; ch[2 * p + 1] = dq[p].y; }
    }
#pragma unroll
    for (int jj = 0; jj < 4; ++jj) {
      f32x2 a = pk_fma(W1h[jj][0], Kn[0], pk_fma(W1h[jj][1], Kn[1], f32x2{0.f, 0.f}));
      f32x2 c = pk_fma(W1h[jj][2], Kn[2], pk_fma(W1h[jj][3], Kn[3], f32x2{0.f, 0.f}));
      f32x2 s = a + c;
      ch[8 + jj] = s.x + s.y;
    }
    {
      f32x2 a = pk_fma(Kc[0], Kn[0], pk_fma(Kc[1], Kn[1], f32x2{0.f, 0.f}));
      f32x2 c = pk_fma(Kc[2], Kn[2], pk_fma(Kc[3], Kn[3], f32x2{0.f, 0.f}));
      f32x2 s = a + c;
      ch[12] = s.x + s.y;
    }
    wreduceN<13>(ch);

    if (lane == 63) {
      exD[cb][w][0] = make_float4(ch[0], ch[1], ch[2], ch[3]);
      exD[cb][w][1] = make_float4(ch[4], ch[5], ch[6], ch[7]);
      exS[cb][w] = make_float4(ch[8] + B1h[0], ch[9] + B1h[1], ch[10] + B1h[2], ch[11] + B1h[3]);
      if (w == 1) exK[cb] = ch[12];
    }

    // ---- W2_{t+1}, b2 (local, off recurrence path) ----
#pragma unroll
    for (int uu = 0; uu < 4; ++uu) {
      f32x2 gv = dd[uu] * f32x2{-LRc, -LRc};
#pragma unroll
      for (int p = 0; p < 4; ++p) W2h[uu][p] = pk_fma(gv, h2[p], W2h[uu][p]);
      B2h[uu] = fmaf(-LRc, dloc[uu], B2h[uu]);
    }

    // ---- rotate streams ----
#pragma unroll
    for (int p = 0; p < 4; ++p) { Kp[p] = Kc[p]; Kc[p] = Kn[p]; }
    Kn[0] = f32x2{ka.x, ka.y}; Kn[1] = f32x2{ka.z, ka.w};
    Kn[2] = f32x2{kb4.x, kb4.y}; Kn[3] = f32x2{kb4.z, kb4.w};
    Vq[0] = vn.x; Vq[1] = vn.y; Vq[2] = vn.z; Vq[3] = vn.w;

    __syncthreads();
  }

  // ---- epilogue: final W1 update with dz_1022 (buf 0), then query ----
  {
    float4 da0 = exD[0][0][0], da1 = exD[0][0][1];
    float4 db0 = exD[0][1][0], db1 = exD[0][1][1];
    float dh[8] = {da0.x + db0.x, da0.y + db0.y, da0.z + db0.z, da0.w + db0.w,
                   da1.x + db1.x, da1.y + db1.y, da1.z + db1.z, da1.w + db1.w};
#pragma unroll
    for (int jj = 0; jj < 4; ++jj) {
      float dzj = (zu[4 * w + jj] > 0.f) ? dh[4 * w + jj] : 0.f;
      float g = -LRc * dzj;
      f32x2 gv = {g, g};
#pragma unroll
      for (int p = 0; p < 4; ++p) W1h[jj][p] = pk_fma(gv, Kp[p], W1h[jj][p]);
      B1h[jj] = fmaf(-LRc, dzj, B1h[jj]);
    }
    const float* pq = hb + (size_t)(Ll - 1) * Hh + c0;
    float4 a = *(const float4*)pq, d = *(const float4*)(pq + 4);
    f32x2 Q[4] = {f32x2{a.x, a.y}, f32x2{a.z, a.w}, f32x2{d.x, d.y}, f32x2{d.z, d.w}};
    float cq[4];
#pragma unroll
    for (int jj = 0; jj < 4; ++jj) {
      f32x2 aa = pk_fma(W1h[jj][0], Q[0], pk_fma(W1h[jj][1], Q[1], f32x2{0.f, 0.f}));
      f32x2 cc = pk_fma(W1h[jj][2], Q[2], pk_fma(W1h[jj][3], Q[3], f32x2{0.f, 0.f}));
      f32x2 s = aa + cc;
      cq[jj] = s.x + s.y;
    }
    wreduceN<4>(cq);
    if (lane == 63)
      exQ[w] = make_float4(cq[0] + B1h[0], cq[1] + B1h[1], cq[2] + B1h[2], cq[3] + B1h[3]);
  }
  __syncthreads();
  {
    float4 q0 = exQ[0], q1 = exQ[1];
    float hq[8] = {fmaxf(q0.x, 0.f), fmaxf(q0.y, 0.f), fmaxf(q0.z, 0.f), fmaxf(q0.w, 0.f),
                   fmaxf(q1.x, 0.f), fmaxf(q1.y, 0.f), fmaxf(q1.z, 0.f), fmaxf(q1.w, 0.f)};
    f32x2 hq2[4];
#pragma unroll
    for (int p = 0; p < 4; ++p) hq2[p] = f32x2{hq[2 * p], hq[2 * p + 1]};
    float o[4];
#pragma unroll
    for (int uu = 0; uu < 4; ++uu) {
      f32x2 a = pk_fma(W2h[uu][0], hq2[0], pk_fma(W2h[uu][1], hq2[1], f32x2{0.f, 0.f}));
      f32x2 c = pk_fma(W2h[uu][2], hq2[2], pk_fma(W2h[uu][3], hq2[3], f32x2{0.f, 0.f}));
      f32x2 s = a + c;
      o[uu] = s.x + s.y + B2h[uu];
    }
    *(float4*)(ctx + (size_t)b * Hh + 8 * lane + 4 * w) = make_float4(o[0], o[1], o[2], o[3]);
  }
}

// ---------------- head: out[b,v] = ctx[b,:] @ out_w[v,:] + out_b[v] ----------------
__global__ __launch_bounds__(256) void out_kernel(const float* __restrict__ ctx,
                                                  const float* __restrict__ outw,
                                                  const float* __restrict__ outb_,
                                                  float* __restrict__ out) {
  __shared__ float cs[16 * 516];
  int tid = threadIdx.x;
#pragma unroll
  for (int r = 0; r < 32; ++r) {
    int idx = r * 256 + tid;
    cs[(idx >> 9) * 516 + (idx & 511)] = ctx[idx];
  }
  __syncthreads();
  int v = blockIdx.x * 16 + (tid >> 4);
  int b = tid & 15;
  const float4* wr = (const float4*)(outw + (size_t)v * 512);
  const float4* cr = (const float4*)(cs + b * 516);
  float acc = 0.f;
#pragma unroll 8
  for (int k = 0; k < 128; ++k) {
    float4 wv = wr[k];
    float4 cv = cr[k];
    acc += wv.x * cv.x + wv.y * cv.y + wv.z * cv.z + wv.w * cv.w;
  }
  out[(size_t)b * 32000 + v] = acc + outb_[v];
}

extern "C" void kernel_launch(void* const* d_in, const int* in_sizes, int n_in,
                              void* d_out, int out_size, void* d_ws, size_t ws_size,
                              hipStream_t stream) {
  const int*   seq    = (const int*)d_in[0];
  const float* embed  = (const float*)d_in[1];
  const float* enc_w1 = (const float*)d_in[2];
  const float* enc_b1 = (const float*)d_in[3];
  const float* enc_w2 = (const float*)d_in[4];
  const float* enc_b2 = (const float*)d_in[5];
  const float* ln_w   = (const float*)d_in[6];
  const float* ln_b   = (const float*)d_in[7];
  const float* mlp_w1 = (const float*)d_in[8];
  const float* mlp_b1 = (const float*)d_in[9];
  const float* mlp_w2 = (const float*)d_in[10];
  const float* mlp_b2 = (const float*)d_in[11];
  const float* out_w  = (const float*)d_in[12];
  const float* out_b  = (const float*)d_in[13];
  float* out = (float*)d_out;

  char* ws = (char*)d_ws;
  float*          xbuf = (float*)(ws + OFF_X);
  unsigned short* ebf  = (unsigned short*)(ws + OFF_EBF);
  unsigned short* w1bf = (unsigned short*)(ws + OFF_W1BF);
  unsigned short* w2bf = (unsigned short*)(ws + OFF_W2BF);
  float*          ctx  = (float*)(ws + OFF_CTX);
  unsigned short* ff1  = (unsigned short*)(ws + OFF_FF1);

  const int cand[4] = {1, 2, 4, 8};
  int nc = 8;
  for (int ci = 0; ci < 4; ++ci) {
    if (OFF_FF1 + (size_t)(Mtot / cand[ci]) * H2 * 2 <= ws_size) { nc = cand[ci]; break; }
  }

  cvt_bf16_kernel<<<2048, 256, 0, stream>>>(embed, ebf, Vv * Hh / 8);
  cvt_bf16_kernel<<<256, 256, 0, stream>>>(enc_w1, w1bf, H2 * Hh / 8);
  cvt_bf16_kernel<<<256, 256, 0, stream>>>(enc_w2, w2bf, Hh * H2 / 8);

  const int Mc = Mtot / nc;
  for (int c = 0; c < nc; ++c) {
    const int m0 = c * Mc;
    gemm_bt<512, true, true><<<dim3(Mc / 128, 8), 256, 0, stream>>>(
        ebf, seq, m0, w1bf, enc_b1, ff1, nullptr, 0, H2);
    gemm_bt<1024, false, false><<<dim3(Mc / 128, 4), 256, 0, stream>>>(
        ff1, nullptr, 0, w2bf, enc_b2, nullptr, xbuf, m0, Hh);
  }
  ln_kernel<<<Mtot / 4, 256, 0, stream>>>(xbuf, embed, seq, ln_w, ln_b);
  ttt_kernel<<<Bb, 128, 0, stream>>>(xbuf, mlp_w1, mlp_b1, mlp_w2, mlp_b2, ctx);
  out_kernel<<<Vv / 16, 256, 0, stream>>>(ctx, out_w, out_b, out);
}